// Round 2
// baseline (279.857 us; speedup 1.0000x reference)
//
#include <hip/hip_runtime.h>
#include <stdint.h>

#define NUM_NODES 17185
#define DD 6
#define FEATS (NUM_NODES * DD)   // 103110
#define BATCH 256
#define EPS 1e-5f

#define NC 256   // nodes per chunk (== block threads, 1 node/thread)
#define BC 16    // batch rows per block

// C = sum_f (beta[f] - mean[f]*scale[f]) * fc_w[f], scale = gamma*rsqrt(var+eps)
__global__ void cprep_kernel(const float* __restrict__ beta, const float* __restrict__ mean,
                             const float* __restrict__ gamma, const float* __restrict__ var,
                             const float* __restrict__ fcw, float* __restrict__ c_out) {
    int tid = blockIdx.x * blockDim.x + threadIdx.x;
    int stride = gridDim.x * blockDim.x;
    float local = 0.f;
    for (int f = tid; f < FEATS; f += stride) {
        float sc = gamma[f] * rsqrtf(var[f] + EPS);
        local += (beta[f] - mean[f] * sc) * fcw[f];
    }
    #pragma unroll
    for (int off = 32; off; off >>= 1) local += __shfl_down(local, off);
    if ((threadIdx.x & 63) == 0) atomicAdd(c_out, local);
}

// Per (node-chunk, batch-chunk) block: thread t owns node chunk+t, 48 params in regs,
// loops BC batch rows streaming x, wave-reduce + one atomic per wave into yacc[b].
__global__ __launch_bounds__(NC) void main_kernel(
    const float* __restrict__ data, const float* __restrict__ wb, const float* __restrict__ bb,
    const float* __restrict__ gamma, const float* __restrict__ var, const float* __restrict__ fcw,
    float* __restrict__ yacc) {

    const int tid = threadIdx.x;
    const int n = blockIdx.x * NC + tid;
    const bool valid = (n < NUM_NODES);

    float wreg[36], bias[6], a[6];
    #pragma unroll
    for (int k = 0; k < 36; k++) wreg[k] = 0.f;
    #pragma unroll
    for (int k = 0; k < 6; k++) { bias[k] = 0.f; a[k] = 0.f; }

    if (valid) {
        // w_blocks[n][o][i]: 36 contiguous fp32 per node; byte stride 144 -> 16-aligned
        const float4* wp = (const float4*)(wb + (size_t)n * 36);
        #pragma unroll
        for (int k = 0; k < 9; k++) {
            float4 v = wp[k];
            wreg[4*k] = v.x; wreg[4*k+1] = v.y; wreg[4*k+2] = v.z; wreg[4*k+3] = v.w;
        }
        const float2* bp = (const float2*)(bb + (size_t)n * 6);
        #pragma unroll
        for (int k = 0; k < 3; k++) { float2 v = bp[k]; bias[2*k] = v.x; bias[2*k+1] = v.y; }
        const int f0 = n * 6;
        const float2* gp = (const float2*)(gamma + f0);
        const float2* vp = (const float2*)(var + f0);
        const float2* fp = (const float2*)(fcw + f0);
        #pragma unroll
        for (int k = 0; k < 3; k++) {
            float2 g = gp[k], v = vp[k], f = fp[k];
            a[2*k]   = g.x * rsqrtf(v.x + EPS) * f.x;
            a[2*k+1] = g.y * rsqrtf(v.y + EPS) * f.y;
        }
    }

    const int b0 = blockIdx.y * BC;
    #pragma unroll 2
    for (int r = 0; r < BC; r++) {
        const int b = b0 + r;
        float acc = 0.f;
        if (valid) {
            // x[b, n*6 .. n*6+5]: byte offset 4*(b*FEATS + 6n), multiple of 8
            const float2* xp = (const float2*)(data + (size_t)b * FEATS + (size_t)n * 6);
            float2 u0 = xp[0], u1 = xp[1], u2 = xp[2];
            float x0 = u0.x, x1 = u0.y, x2 = u1.x, x3 = u1.y, x4 = u2.x, x5 = u2.y;
            #pragma unroll
            for (int o = 0; o < 6; o++) {
                float s = bias[o];
                s = fmaf(x0, wreg[o*6+0], s);
                s = fmaf(x1, wreg[o*6+1], s);
                s = fmaf(x2, wreg[o*6+2], s);
                s = fmaf(x3, wreg[o*6+3], s);
                s = fmaf(x4, wreg[o*6+4], s);
                s = fmaf(x5, wreg[o*6+5], s);
                acc = fmaf(fmaxf(s, 0.f), a[o], acc);
            }
        }
        #pragma unroll
        for (int off = 32; off; off >>= 1) acc += __shfl_down(acc, off);
        if ((tid & 63) == 0) atomicAdd(&yacc[b], acc);
    }
}

__global__ void final_kernel(const float* __restrict__ yacc, const float* __restrict__ c_sum,
                             const float* __restrict__ fcb, const float* __restrict__ bnfg,
                             const float* __restrict__ bnfb, const float* __restrict__ bnfm,
                             const float* __restrict__ bnfv, float* __restrict__ out) {
    int b = threadIdx.x;
    float y = yacc[b] + c_sum[0] + fcb[0];
    float sc = bnfg[0] * rsqrtf(bnfv[0] + EPS);
    float z = (y - bnfm[0]) * sc + bnfb[0];
    out[b] = 1.f / (1.f + expf(-z));
}

extern "C" void kernel_launch(void* const* d_in, const int* in_sizes, int n_in,
                              void* d_out, int out_size, void* d_ws, size_t ws_size,
                              hipStream_t stream) {
    const float* data  = (const float*)d_in[0];
    const float* wb    = (const float*)d_in[1];
    const float* bb    = (const float*)d_in[2];
    const float* gamma = (const float*)d_in[3];
    const float* beta  = (const float*)d_in[4];
    const float* mean  = (const float*)d_in[5];
    const float* var   = (const float*)d_in[6];
    const float* fcw   = (const float*)d_in[7];
    const float* fcb   = (const float*)d_in[8];
    const float* bnfg  = (const float*)d_in[9];
    const float* bnfb  = (const float*)d_in[10];
    const float* bnfm  = (const float*)d_in[11];
    const float* bnfv  = (const float*)d_in[12];

    float* yacc  = (float*)d_ws;          // 256 floats
    float* c_sum = yacc + 256;            // 1 float

    hipMemsetAsync(d_ws, 0, 1280, stream);
    cprep_kernel<<<64, 256, 0, stream>>>(beta, mean, gamma, var, fcw, c_sum);

    dim3 grid((NUM_NODES + NC - 1) / NC, BATCH / BC);  // (68, 16)
    main_kernel<<<grid, NC, 0, stream>>>(data, wb, bb, gamma, var, fcw, yacc);

    final_kernel<<<1, BATCH, 0, stream>>>(yacc, c_sum, fcb, bnfg, bnfb, bnfm, bnfv, (float*)d_out);
}

// Round 3
// 191.649 us; speedup vs baseline: 1.4603x; 1.4603x over previous
//
#include <hip/hip_runtime.h>
#include <stdint.h>

#define NUM_NODES 17185
#define DD 6
#define FEATS (NUM_NODES * DD)   // 103110
#define BATCH 256
#define EPS 1e-5f

#define NC 256   // nodes per block (== threads, 1 node/thread)
#define BC 8     // batch rows per block
#define NCHUNK ((NUM_NODES + NC - 1) / NC)   // 68
#define CPREP_BLOCKS 256

// ws layout: pm[NCHUNK*256] (row partials, chunk-major), pc[CPREP_BLOCKS]
// No atomics anywhere: every slot written exactly once -> deterministic.

__global__ __launch_bounds__(256) void cprep_kernel(
    const float* __restrict__ beta, const float* __restrict__ mean,
    const float* __restrict__ gamma, const float* __restrict__ var,
    const float* __restrict__ fcw, float* __restrict__ pc) {
    int tid = blockIdx.x * blockDim.x + threadIdx.x;
    int stride = gridDim.x * blockDim.x;
    float local = 0.f;
    for (int f = tid; f < FEATS; f += stride) {
        float sc = gamma[f] * rsqrtf(var[f] + EPS);
        local += (beta[f] - mean[f] * sc) * fcw[f];
    }
    #pragma unroll
    for (int off = 32; off; off >>= 1) local += __shfl_down(local, off);
    __shared__ float red[4];
    if ((threadIdx.x & 63) == 0) red[threadIdx.x >> 6] = local;
    __syncthreads();
    if (threadIdx.x == 0) pc[blockIdx.x] = red[0] + red[1] + red[2] + red[3];
}

__global__ __launch_bounds__(NC) void main_kernel(
    const float* __restrict__ data, const float* __restrict__ wb, const float* __restrict__ bb,
    const float* __restrict__ gamma, const float* __restrict__ var, const float* __restrict__ fcw,
    float* __restrict__ pm) {

    const int tid = threadIdx.x;
    const int n = blockIdx.x * NC + tid;
    const bool valid = (n < NUM_NODES);

    float wreg[36], bias[6], a[6];
    #pragma unroll
    for (int k = 0; k < 36; k++) wreg[k] = 0.f;
    #pragma unroll
    for (int k = 0; k < 6; k++) { bias[k] = 0.f; a[k] = 0.f; }

    if (valid) {
        const float4* wp = (const float4*)(wb + (size_t)n * 36);   // 144B stride, 16-aligned
        #pragma unroll
        for (int k = 0; k < 9; k++) {
            float4 v = wp[k];
            wreg[4*k] = v.x; wreg[4*k+1] = v.y; wreg[4*k+2] = v.z; wreg[4*k+3] = v.w;
        }
        const float2* bp = (const float2*)(bb + (size_t)n * 6);
        #pragma unroll
        for (int k = 0; k < 3; k++) { float2 v = bp[k]; bias[2*k] = v.x; bias[2*k+1] = v.y; }
        const int f0 = n * 6;
        const float2* gp = (const float2*)(gamma + f0);
        const float2* vp = (const float2*)(var + f0);
        const float2* fp = (const float2*)(fcw + f0);
        #pragma unroll
        for (int k = 0; k < 3; k++) {
            float2 g = gp[k], v = vp[k], f = fp[k];
            a[2*k]   = g.x * rsqrtf(v.x + EPS) * f.x;
            a[2*k+1] = g.y * rsqrtf(v.y + EPS) * f.y;
        }
    }

    const int b0 = blockIdx.y * BC;
    float acc[BC];
    #pragma unroll
    for (int r = 0; r < BC; r++) acc[r] = 0.f;

    if (valid) {
        const float2* xbase = (const float2*)(data + (size_t)b0 * FEATS + (size_t)n * 6);
        #pragma unroll
        for (int r = 0; r < BC; r++) {
            const float2* xp = xbase + (size_t)r * (FEATS / 2);
            float2 u0 = xp[0], u1 = xp[1], u2 = xp[2];
            float x0 = u0.x, x1 = u0.y, x2 = u1.x, x3 = u1.y, x4 = u2.x, x5 = u2.y;
            float s;
            #pragma unroll
            for (int o = 0; o < 6; o++) {
                s = bias[o];
                s = fmaf(x0, wreg[o*6+0], s);
                s = fmaf(x1, wreg[o*6+1], s);
                s = fmaf(x2, wreg[o*6+2], s);
                s = fmaf(x3, wreg[o*6+3], s);
                s = fmaf(x4, wreg[o*6+4], s);
                s = fmaf(x5, wreg[o*6+5], s);
                acc[r] = fmaf(fmaxf(s, 0.f), a[o], acc[r]);
            }
        }
    }

    // Block reduction: 8 independent 6-deep shuffle chains (good ILP), once per block.
    __shared__ float red[4][BC];
    #pragma unroll
    for (int r = 0; r < BC; r++) {
        float v = acc[r];
        #pragma unroll
        for (int off = 32; off; off >>= 1) v += __shfl_down(v, off);
        if ((tid & 63) == 0) red[tid >> 6][r] = v;
    }
    __syncthreads();
    if (tid < BC) {
        float s = red[0][tid] + red[1][tid] + red[2][tid] + red[3][tid];
        pm[blockIdx.x * 256 + b0 + tid] = s;   // chunk-major for coalesced final read
    }
}

__global__ __launch_bounds__(256) void final_kernel(
    const float* __restrict__ pm, const float* __restrict__ pc,
    const float* __restrict__ fcb, const float* __restrict__ bnfg,
    const float* __restrict__ bnfb, const float* __restrict__ bnfm,
    const float* __restrict__ bnfv, float* __restrict__ out) {
    const int b = threadIdx.x;

    // Reduce pc[256] across the block once.
    float c = pc[b];
    #pragma unroll
    for (int off = 32; off; off >>= 1) c += __shfl_down(c, off);
    __shared__ float red[4];
    if ((b & 63) == 0) red[b >> 6] = c;
    __syncthreads();
    const float c_sum = red[0] + red[1] + red[2] + red[3];

    float y = 0.f;
    for (int ch = 0; ch < NCHUNK; ch++) y += pm[ch * 256 + b];   // coalesced

    y += c_sum + fcb[0];
    float sc = bnfg[0] * rsqrtf(bnfv[0] + EPS);
    float z = (y - bnfm[0]) * sc + bnfb[0];
    out[b] = 1.f / (1.f + expf(-z));
}

extern "C" void kernel_launch(void* const* d_in, const int* in_sizes, int n_in,
                              void* d_out, int out_size, void* d_ws, size_t ws_size,
                              hipStream_t stream) {
    const float* data  = (const float*)d_in[0];
    const float* wb    = (const float*)d_in[1];
    const float* bb    = (const float*)d_in[2];
    const float* gamma = (const float*)d_in[3];
    const float* beta  = (const float*)d_in[4];
    const float* mean  = (const float*)d_in[5];
    const float* var   = (const float*)d_in[6];
    const float* fcw   = (const float*)d_in[7];
    const float* fcb   = (const float*)d_in[8];
    const float* bnfg  = (const float*)d_in[9];
    const float* bnfb  = (const float*)d_in[10];
    const float* bnfm  = (const float*)d_in[11];
    const float* bnfv  = (const float*)d_in[12];

    float* pm = (float*)d_ws;                 // NCHUNK*256 floats
    float* pc = pm + NCHUNK * 256;            // CPREP_BLOCKS floats

    cprep_kernel<<<CPREP_BLOCKS, 256, 0, stream>>>(beta, mean, gamma, var, fcw, pc);

    dim3 grid(NCHUNK, BATCH / BC);            // (68, 32) = 2176 blocks
    main_kernel<<<grid, NC, 0, stream>>>(data, wb, bb, gamma, var, fcw, pm);

    final_kernel<<<1, 256, 0, stream>>>(pm, pc, fcb, bnfg, bnfb, bnfm, bnfv, (float*)d_out);
}

// Round 4
// 191.446 us; speedup vs baseline: 1.4618x; 1.0011x over previous
//
#include <hip/hip_runtime.h>
#include <stdint.h>

#define NUM_NODES 17185
#define DD 6
#define FEATS (NUM_NODES * DD)   // 103110
#define BATCH 256
#define EPS 1e-5f

#define NC 256   // nodes per block (== threads, 1 node/thread)
#define BC 16    // batch rows per block
#define NCHUNK ((NUM_NODES + NC - 1) / NC)   // 68

// ws layout: pm[NCHUNK*256] (row partials, chunk-major), pc[NCHUNK]
// No atomics: every ws slot written exactly once -> deterministic, no zeroing needed.

__global__ __launch_bounds__(NC) void main_kernel(
    const float* __restrict__ data, const float* __restrict__ wb, const float* __restrict__ bb,
    const float* __restrict__ gamma, const float* __restrict__ var, const float* __restrict__ fcw,
    const float* __restrict__ beta, const float* __restrict__ mean,
    float* __restrict__ pm, float* __restrict__ pc) {

    const int tid = threadIdx.x;
    const int n = blockIdx.x * NC + tid;
    const bool valid = (n < NUM_NODES);

    float wreg[36], bias[6], a[6];
    #pragma unroll
    for (int k = 0; k < 36; k++) wreg[k] = 0.f;
    #pragma unroll
    for (int k = 0; k < 6; k++) { bias[k] = 0.f; a[k] = 0.f; }

    float cnode = 0.f;   // per-node contribution to the BN constant (only y==0 blocks)

    if (valid) {
        const float4* wp = (const float4*)(wb + (size_t)n * 36);   // 144B stride, 16-aligned
        #pragma unroll
        for (int k = 0; k < 9; k++) {
            float4 v = wp[k];
            wreg[4*k] = v.x; wreg[4*k+1] = v.y; wreg[4*k+2] = v.z; wreg[4*k+3] = v.w;
        }
        const float2* bp = (const float2*)(bb + (size_t)n * 6);
        #pragma unroll
        for (int k = 0; k < 3; k++) { float2 v = bp[k]; bias[2*k] = v.x; bias[2*k+1] = v.y; }
        const int f0 = n * 6;
        const float2* gp = (const float2*)(gamma + f0);
        const float2* vp = (const float2*)(var + f0);
        const float2* fp = (const float2*)(fcw + f0);
        float fw[6];
        #pragma unroll
        for (int k = 0; k < 3; k++) {
            float2 g = gp[k], v = vp[k], f = fp[k];
            fw[2*k] = f.x; fw[2*k+1] = f.y;
            a[2*k]   = g.x * rsqrtf(v.x + EPS) * f.x;
            a[2*k+1] = g.y * rsqrtf(v.y + EPS) * f.y;
        }
        if (blockIdx.y == 0) {
            // c contribution: sum_o beta[o]*fcw[o] - mean[o]*a[o]
            const float2* bep = (const float2*)(beta + f0);
            const float2* mp  = (const float2*)(mean + f0);
            #pragma unroll
            for (int k = 0; k < 3; k++) {
                float2 be = bep[k], m = mp[k];
                cnode += be.x * fw[2*k]   - m.x * a[2*k];
                cnode += be.y * fw[2*k+1] - m.y * a[2*k+1];
            }
        }
    }

    const int b0 = blockIdx.y * BC;
    float acc[BC];
    #pragma unroll
    for (int r = 0; r < BC; r++) acc[r] = 0.f;

    if (valid) {
        const float2* xbase = (const float2*)(data + (size_t)b0 * FEATS + (size_t)n * 6);
        #pragma unroll
        for (int r = 0; r < BC; r++) {
            const float2* xp = xbase + (size_t)r * (FEATS / 2);
            float2 u0 = xp[0], u1 = xp[1], u2 = xp[2];
            float x0 = u0.x, x1 = u0.y, x2 = u1.x, x3 = u1.y, x4 = u2.x, x5 = u2.y;
            #pragma unroll
            for (int o = 0; o < 6; o++) {
                float s = bias[o];
                s = fmaf(x0, wreg[o*6+0], s);
                s = fmaf(x1, wreg[o*6+1], s);
                s = fmaf(x2, wreg[o*6+2], s);
                s = fmaf(x3, wreg[o*6+3], s);
                s = fmaf(x4, wreg[o*6+4], s);
                s = fmaf(x5, wreg[o*6+5], s);
                acc[r] = fmaf(fmaxf(s, 0.f), a[o], acc[r]);
            }
        }
    }

    // Block reduction: BC independent 6-deep shuffle chains, once per block.
    __shared__ float red[4][BC];
    #pragma unroll
    for (int r = 0; r < BC; r++) {
        float v = acc[r];
        #pragma unroll
        for (int off = 32; off; off >>= 1) v += __shfl_down(v, off);
        if ((tid & 63) == 0) red[tid >> 6][r] = v;
    }

    if (blockIdx.y == 0) {
        float v = cnode;
        #pragma unroll
        for (int off = 32; off; off >>= 1) v += __shfl_down(v, off);
        __shared__ float credd[4];
        if ((tid & 63) == 0) credd[tid >> 6] = v;
        __syncthreads();
        if (tid == 0) pc[blockIdx.x] = credd[0] + credd[1] + credd[2] + credd[3];
    } else {
        __syncthreads();
    }

    if (tid < BC) {
        float s = red[0][tid] + red[1][tid] + red[2][tid] + red[3][tid];
        pm[blockIdx.x * 256 + b0 + tid] = s;   // chunk-major for coalesced final read
    }
}

__global__ __launch_bounds__(256) void final_kernel(
    const float* __restrict__ pm, const float* __restrict__ pc,
    const float* __restrict__ fcb, const float* __restrict__ bnfg,
    const float* __restrict__ bnfb, const float* __restrict__ bnfm,
    const float* __restrict__ bnfv, float* __restrict__ out) {
    const int b = threadIdx.x;

    // Reduce pc[NCHUNK] across the block once.
    float c = (b < NCHUNK) ? pc[b] : 0.f;
    #pragma unroll
    for (int off = 32; off; off >>= 1) c += __shfl_down(c, off);
    __shared__ float red[4];
    if ((b & 63) == 0) red[b >> 6] = c;
    __syncthreads();
    const float c_sum = red[0] + red[1] + red[2] + red[3];

    float y = 0.f;
    #pragma unroll 4
    for (int ch = 0; ch < NCHUNK; ch++) y += pm[ch * 256 + b];   // coalesced

    y += c_sum + fcb[0];
    float sc = bnfg[0] * rsqrtf(bnfv[0] + EPS);
    float z = (y - bnfm[0]) * sc + bnfb[0];
    out[b] = 1.f / (1.f + expf(-z));
}

extern "C" void kernel_launch(void* const* d_in, const int* in_sizes, int n_in,
                              void* d_out, int out_size, void* d_ws, size_t ws_size,
                              hipStream_t stream) {
    const float* data  = (const float*)d_in[0];
    const float* wb    = (const float*)d_in[1];
    const float* bb    = (const float*)d_in[2];
    const float* gamma = (const float*)d_in[3];
    const float* beta  = (const float*)d_in[4];
    const float* mean  = (const float*)d_in[5];
    const float* var   = (const float*)d_in[6];
    const float* fcw   = (const float*)d_in[7];
    const float* fcb   = (const float*)d_in[8];
    const float* bnfg  = (const float*)d_in[9];
    const float* bnfb  = (const float*)d_in[10];
    const float* bnfm  = (const float*)d_in[11];
    const float* bnfv  = (const float*)d_in[12];

    float* pm = (float*)d_ws;                 // NCHUNK*256 floats
    float* pc = pm + NCHUNK * 256;            // NCHUNK floats

    dim3 grid(NCHUNK, BATCH / BC);            // (68, 16) = 1088 blocks
    main_kernel<<<grid, NC, 0, stream>>>(data, wb, bb, gamma, var, fcw, beta, mean, pm, pc);

    final_kernel<<<1, 256, 0, stream>>>(pm, pc, fcb, bnfg, bnfb, bnfm, bnfv, (float*)d_out);
}